// Round 9
// baseline (578.923 us; speedup 1.0000x reference)
//
#include <hip/hip_runtime.h>
#include <math.h>

#define B 1024
#define T 512
#define S 48
#define SOS 47

// broadcast lane l's value to all lanes via the SGPR file (VALU op)
__device__ __forceinline__ float rdlanef(float v, int l) {
    return __int_as_float(__builtin_amdgcn_readlane(__float_as_int(v), l));
}

// ---------------------------------------------------------------------------
// Fused CRF loss. One wave per TWO rows; lane i owns state i for both.
// Scan kept in exp space with DELAYED normalization (per stream):
//   invariant  u_t = q * exp(M)   (exact; r_s == exp(-l_s) pending factor)
//   live step: q' = (expT q) * exp(emis - er) * r_s ;  M += er + l_s
//              then r_s = rcp(d1), l_s = log(d1)   [off critical chain]
//
// ROUND 9: TWO INDEPENDENT SCAN STREAMS PER WAVE (dual-batch ILP).
// Ledger closed on instruction-count attacks:
//   r1 48rl+48fma           145us  busy ~222cyc/step, VALUBusy 60%
//   r6/r8 pk_fma variants   149/150us -- NEUTRAL, and now explained:
//     157.3TF fp32 = 256CU x 4SIMD x 32lane x 2FLOP x 2.4GHz, NO packed
//     factor. v_pk_fma_f32 is throughput-neutral on CDNA4 (2 floats over
//     2x cycles); busy-cycles never dropped. pk/batching chapter closed.
//   r2/r4 DS transport      189/345us -- DS pipe loses, closed.
//   r7 per-elem SGPR select 276us -- scalarization untrustworthy, closed.
// Remaining resource: the ~40% per-step idle (~120 stall cyc: select->
// readlane joints, rl->SGPR hazards, fma dependent latency) with zero TLP
// at 1 wave/SIMD. Fix: interleave batch A and batch B in one wave. The two
// chains are register-disjoint and independent -> each stream's stalls are
// filled by the other's ready instructions. Per-wave busy/step ~2x, but
// per-BATCH step cost ~ (2*222+eps)/2 ~= 225 cyc vs 341 -> ~1.4x.
// 512 blocks still fully concurrent (512 of 1024 SIMDs; wall = wave time).
// expT is SHARED by both streams (one copy in VGPRs). Rings duplicate.
// Outer unroll-2 dropped to keep the 2x body inside I$.
// Each stream's math is instruction-for-instruction round 1 -> absmax 0.0.
// amdgpu_waves_per_eu(1): full VGPR budget (structurally 1 wave/SIMD).
// ---------------------------------------------------------------------------
__global__ __launch_bounds__(64, 1)
__attribute__((amdgpu_waves_per_eu(1)))
void crf_fused(const float* __restrict__ feat,
               const int* __restrict__ states,
               const float* __restrict__ mask,
               const float* __restrict__ trans,
               float* __restrict__ out) {
    const int b0 = blockIdx.x * 2;              // this wave's two batches
    const int lane = threadIdx.x;
    const int elane = (lane < S) ? lane : 0;    // lanes 48-63 shadow lane 0
    const float* fA = feat + (size_t)b0 * T * S;
    const float* fB = fA + (size_t)T * S;
    const float* mA = mask + (size_t)b0 * T;
    const float* mB = mA + T;
    const int* sA = states + (size_t)b0 * T;
    const int* sB = sA + T;

    // ---- numerators (latency overlaps expT setup) ----
    float nsA = 0.f, nsB = 0.f;
#pragma unroll
    for (int k2 = 0; k2 < T / 64; ++k2) {
        const int t = lane + k2 * 64;
        const int stA = sA[t];
        const int pvA = (t == 0) ? SOS : sA[t - 1];
        nsA += (fA[t * S + stA] + trans[stA * S + pvA]) * mA[t];
        const int stB = sB[t];
        const int pvB = (t == 0) ? SOS : sB[t - 1];
        nsB += (fB[t * S + stB] + trans[stB * S + pvB]) * mB[t];
    }

    // ---- expT row for this lane (SHARED by both streams);
    //      exp(-9999) underflows to exact 0 ----
    float expT[S];
    {
        const float4* t4 = (const float4*)(trans + elane * S);
#pragma unroll
        for (int j4 = 0; j4 < S / 4; ++j4) {
            const float4 tv = t4[j4];
            expT[4 * j4 + 0] = (lane < S) ? __expf(tv.x) : 0.f;
            expT[4 * j4 + 1] = (lane < S) ? __expf(tv.y) : 0.f;
            expT[4 * j4 + 2] = (lane < S) ? __expf(tv.z) : 0.f;
            expT[4 * j4 + 3] = (lane < S) ? __expf(tv.w) : 0.f;
        }
    }

    // ---- scan state, two independent streams ----
    float qA = (lane == SOS) ? 1.f : 0.f;       // lanes >= 48 hold 0 forever
    float qB = qA;
    float MA = 0.f, MB = 0.f;
    float rA = 1.f, lA = 0.f;        // pending normalizer: rA == exp(-lA)
    float rB = 1.f, lB = 0.f;

    // emission/mask double-buffered block rings (8 steps per block) x2
    float eringA[2][8], mringA[2][8], eringB[2][8], mringB[2][8];
#pragma unroll
    for (int k = 0; k < 8; ++k) {
        eringA[0][k] = fA[k * S + elane];
        mringA[0][k] = mA[k];
        eringB[0][k] = fB[k * S + elane];
        mringB[0][k] = mB[k];
    }

    for (int tb = 0; tb < T / 8; ++tb) {
        const int pb = tb & 1;
        // issue next block's loads now; consumed a full block later
        const int tn = ((tb + 1) & (T / 8 - 1)) * 8;   // wrap: last refill unused
#pragma unroll
        for (int k = 0; k < 8; ++k) {
            eringA[pb ^ 1][k] = fA[(tn + k) * S + elane];
            mringA[pb ^ 1][k] = mA[tn + k];
            eringB[pb ^ 1][k] = fB[(tn + k) * S + elane];
            mringB[pb ^ 1][k] = mB[tn + k];
        }
#pragma unroll
        for (int k = 0; k < 8; ++k) {
            // off-chain: per-lane factors from prefetched emissions
            const float emisA = eringA[pb][k];
            const float emisB = eringB[pb][k];
            const float erA = rdlanef(emisA, 1);
            const float erB = rdlanef(emisB, 1);
            const float FA = __expf(emisA - erA) * rA;
            const float FB = __expf(emisB - erB) * rB;
            // chains: dot d_i = expT[i] . q, two streams interleaved.
            // Each stream is instruction-for-instruction round 1; the
            // scheduler fills one stream's rl/fma hazards with the other's
            // ready ops.
            float axA = 0.f, ayA = 0.f, azA = 0.f, awA = 0.f;
            float axB = 0.f, ayB = 0.f, azB = 0.f, awB = 0.f;
#pragma unroll
            for (int j4 = 0; j4 < S / 4; ++j4) {
                axA = fmaf(expT[4 * j4 + 0], rdlanef(qA, 4 * j4 + 0), axA);
                axB = fmaf(expT[4 * j4 + 0], rdlanef(qB, 4 * j4 + 0), axB);
                ayA = fmaf(expT[4 * j4 + 1], rdlanef(qA, 4 * j4 + 1), ayA);
                ayB = fmaf(expT[4 * j4 + 1], rdlanef(qB, 4 * j4 + 1), ayB);
                azA = fmaf(expT[4 * j4 + 2], rdlanef(qA, 4 * j4 + 2), azA);
                azB = fmaf(expT[4 * j4 + 2], rdlanef(qB, 4 * j4 + 2), azB);
                awA = fmaf(expT[4 * j4 + 3], rdlanef(qA, 4 * j4 + 3), awA);
                awB = fmaf(expT[4 * j4 + 3], rdlanef(qB, 4 * j4 + 3), awB);
            }
            const float dA = (axA + ayA) + (azA + awA);
            const float dB = (axB + ayB) + (azB + awB);
            const float qnA = dA * FA;
            const float qnB = dB * FB;
            const bool liveA = (mringA[pb][k] != 0.f);
            const bool liveB = (mringB[pb][k] != 0.f);
            qA = liveA ? qnA : qA;              // SELECT, never blend
            qB = liveB ? qnB : qB;
            // off-chain: next normalizers + shift bookkeeping
            MA = liveA ? (MA + erA + lA) : MA;  // uses OLD lA, then update
            MB = liveB ? (MB + erB + lB) : MB;
            const float drA = rdlanef(dA, 1);   // lane1 dot: provably > 0
            const float drB = rdlanef(dB, 1);
            const float nlA = __logf(drA);
            const float nlB = __logf(drB);
            const float nrA = __builtin_amdgcn_rcpf(drA);
            const float nrB = __builtin_amdgcn_rcpf(drB);
            rA = liveA ? nrA : rA;
            lA = liveA ? nlA : lA;
            rB = liveB ? nrB : rB;
            lB = liveB ? nlB : lB;
        }
    }

    // ---- epilogue: denom = M + log(sum_i q_i); out = denom - numer ----
    float psA = qA, psB = qB;                   // lanes >= 48 hold 0
#pragma unroll
    for (int off = 32; off > 0; off >>= 1) {
        psA += __shfl_xor(psA, off, 64);
        psB += __shfl_xor(psB, off, 64);
        nsA += __shfl_xor(nsA, off, 64);
        nsB += __shfl_xor(nsB, off, 64);
    }
    if (lane == 0) {
        out[b0] = MA + __logf(psA) - nsA;
        out[b0 + 1] = MB + __logf(psB) - nsB;
    }
}

extern "C" void kernel_launch(void* const* d_in, const int* in_sizes, int n_in,
                              void* d_out, int out_size, void* d_ws, size_t ws_size,
                              hipStream_t stream) {
    const float* feat   = (const float*)d_in[0];   // (B,T,S) f32
    const int*   states = (const int*)d_in[1];     // (B,T) i32
    const float* mask   = (const float*)d_in[2];   // (B,T) f32
    const float* trans  = (const float*)d_in[3];   // (S,S) f32
    float* out = (float*)d_out;                    // (B,) f32

    crf_fused<<<dim3(B / 2), dim3(64), 0, stream>>>(feat, states, mask, trans, out);
}

// Round 10
// 257.175 us; speedup vs baseline: 2.2511x; 2.2511x over previous
//
#include <hip/hip_runtime.h>
#include <math.h>

#define B 1024
#define T 512
#define S 48
#define SOS 47

// broadcast lane l's value to all lanes via the SGPR file (VALU op)
__device__ __forceinline__ float rdlanef(float v, int l) {
    return __int_as_float(__builtin_amdgcn_readlane(__float_as_int(v), l));
}

// ---------------------------------------------------------------------------
// Fused CRF loss. One wave per row; lane i owns state i; expT row in VGPRs.
// Scan kept in exp space with DELAYED normalization:
//   invariant  u_t = q * exp(M)   (exact; r_s == exp(-l_s) pending factor)
//   live step: q' = (expT q) * exp(emis - er) * r_s ;  M += er + l_s
//              then r_s = rcp(d1), l_s = log(d1)   [off critical chain]
//
// ROUND 10: r1 (145us, best) + FORCED REGISTER RESIDENCY of the ring
// prefetch. Ledger:
//   r1  48rl+48fma            145us  VGPR=56 (!), VALUBusy 60%
//   r6/r8 pk_fma/batched      149/150us  neutral (pk is 2x cyc on CDNA4;
//        issue-cycles never dropped -- instruction-count chapter closed)
//   r2/r4 DS transport        189/345us  DS pipe loses, closed
//   r7  per-elem SGPR select  276us  scalarization untrustworthy, closed
//   r9  dual-stream           472us  (a) runtime pb -> rings in SCRATCH
//        (rule #20); (b) arithmetically unsound anyway: wall = per-wave
//        time, 2x busy/step (444cyc) > r1's total 341. TLP closed.
// The surviving anomaly: r1's VGPR=56 < expT(48)+rings(32)+state. The
// rings were NEVER register-resident -- the compiler SANK the prefetch
// loads to their uses, so every step pays ~100cyc of vmem wait. That
// closes the books: 341 cyc/step = ~240 issue floor + ~100 vmem stall.
// Fix: operand-only asm touch of all 16 next-block ring values at the END
// of each 8-step block. Forces: loads issued at block start, waited ~2700
// cyc later (hidden), consumed next block as pure register reads.
// Math byte-identical to r1 -> absmax 0.0.
// amdgpu_waves_per_eu(1): full VGPR budget (structurally 1 wave/SIMD).
// ---------------------------------------------------------------------------
__global__ __launch_bounds__(64, 1)
__attribute__((amdgpu_waves_per_eu(1)))
void crf_fused(const float* __restrict__ feat,
               const int* __restrict__ states,
               const float* __restrict__ mask,
               const float* __restrict__ trans,
               float* __restrict__ out) {
    const int b = blockIdx.x;
    const int lane = threadIdx.x;
    const int elane = (lane < S) ? lane : 0;    // lanes 48-63 shadow lane 0
    const float* f_b = feat + (size_t)b * T * S;
    const float* m_b = mask + b * T;
    const int* st_b = states + b * T;

    // ---- numerator (latency overlaps expT setup) ----
    float nsum = 0.f;
#pragma unroll
    for (int k2 = 0; k2 < T / 64; ++k2) {
        const int t = lane + k2 * 64;
        const int st = st_b[t];
        const int pv = (t == 0) ? SOS : st_b[t - 1];
        nsum += (f_b[t * S + st] + trans[st * S + pv]) * m_b[t];
    }

    // ---- expT row for this lane; exp(-9999) underflows to exact 0 ----
    float expT[S];
    {
        const float4* t4 = (const float4*)(trans + elane * S);
#pragma unroll
        for (int j4 = 0; j4 < S / 4; ++j4) {
            const float4 tv = t4[j4];
            expT[4 * j4 + 0] = (lane < S) ? __expf(tv.x) : 0.f;
            expT[4 * j4 + 1] = (lane < S) ? __expf(tv.y) : 0.f;
            expT[4 * j4 + 2] = (lane < S) ? __expf(tv.z) : 0.f;
            expT[4 * j4 + 3] = (lane < S) ? __expf(tv.w) : 0.f;
        }
    }

    // ---- scan state ----
    float q = (lane == SOS) ? 1.f : 0.f;        // lanes >= 48 hold 0 forever
    float M = 0.f;
    float r_s = 1.f, l_s = 0.f;      // pending normalizer: r_s == exp(-l_s)

    // emission/mask double-buffered block rings (8 steps per block)
    float ering[2][8], mring[2][8];
#pragma unroll
    for (int k = 0; k < 8; ++k) {
        ering[0][k] = f_b[k * S + elane];
        mring[0][k] = m_b[k];
    }
    // force the seed block resident before the scan starts
    asm("" :: "v"(ering[0][0]), "v"(ering[0][1]), "v"(ering[0][2]),
              "v"(ering[0][3]), "v"(ering[0][4]), "v"(ering[0][5]),
              "v"(ering[0][6]), "v"(ering[0][7]));
    asm("" :: "v"(mring[0][0]), "v"(mring[0][1]), "v"(mring[0][2]),
              "v"(mring[0][3]), "v"(mring[0][4]), "v"(mring[0][5]),
              "v"(mring[0][6]), "v"(mring[0][7]));

#pragma unroll 2
    for (int tb = 0; tb < T / 8; ++tb) {
        const int pb = tb & 1;
        // issue next block's loads now; consumed a full block later
        const int tn = ((tb + 1) & (T / 8 - 1)) * 8;   // wrap: last refill unused
#pragma unroll
        for (int k = 0; k < 8; ++k) {
            ering[pb ^ 1][k] = f_b[(tn + k) * S + elane];
            mring[pb ^ 1][k] = m_b[tn + k];
        }
#pragma unroll
        for (int k = 0; k < 8; ++k) {
            // off-chain: per-lane factor from prefetched emission
            const float emis = ering[pb][k];
            const float er = rdlanef(emis, 1);
            const float F = __expf(emis - er) * r_s;
            // chain: SGPR-broadcast dot d_i = expT[i] . q
            // (48 v_readlane + 48 v_fma; round-1 accumulation order)
            float ax = 0.f, ay = 0.f, az = 0.f, aw = 0.f;
#pragma unroll
            for (int j4 = 0; j4 < S / 4; ++j4) {
                ax = fmaf(expT[4 * j4 + 0], rdlanef(q, 4 * j4 + 0), ax);
                ay = fmaf(expT[4 * j4 + 1], rdlanef(q, 4 * j4 + 1), ay);
                az = fmaf(expT[4 * j4 + 2], rdlanef(q, 4 * j4 + 2), az);
                aw = fmaf(expT[4 * j4 + 3], rdlanef(q, 4 * j4 + 3), aw);
            }
            const float d = (ax + ay) + (az + aw);
            const float qn = d * F;
            const bool live = (mring[pb][k] != 0.f);
            q = live ? qn : q;                  // SELECT, never blend
            // off-chain: next normalizer + shift bookkeeping
            M = live ? (M + er + l_s) : M;      // uses OLD l_s, then update
            const float dr = rdlanef(d, 1);     // lane1 dot: provably > 0
            const float nl = __logf(dr);
            const float nr = __builtin_amdgcn_rcpf(dr);
            r_s = live ? nr : r_s;
            l_s = live ? nl : l_s;
        }
        // FORCE next block's ring values into VGPRs HERE, ~8 steps (~2700
        // cyc) after their loads were issued: the s_waitcnt lands here
        // (fully hidden) and next block's consumes are register reads.
        // Operand-only asm (no outputs) is implicitly volatile; under the
        // unroll-2, pb^1 is compile-time so these are SSA values.
        asm("" :: "v"(ering[pb ^ 1][0]), "v"(ering[pb ^ 1][1]),
                  "v"(ering[pb ^ 1][2]), "v"(ering[pb ^ 1][3]),
                  "v"(ering[pb ^ 1][4]), "v"(ering[pb ^ 1][5]),
                  "v"(ering[pb ^ 1][6]), "v"(ering[pb ^ 1][7]));
        asm("" :: "v"(mring[pb ^ 1][0]), "v"(mring[pb ^ 1][1]),
                  "v"(mring[pb ^ 1][2]), "v"(mring[pb ^ 1][3]),
                  "v"(mring[pb ^ 1][4]), "v"(mring[pb ^ 1][5]),
                  "v"(mring[pb ^ 1][6]), "v"(mring[pb ^ 1][7]));
    }

    // ---- epilogue: denom = M + log(sum_i q_i); out = denom - numer ----
    float ps = q;                               // lanes >= 48 hold 0
#pragma unroll
    for (int off = 32; off > 0; off >>= 1) {
        ps += __shfl_xor(ps, off, 64);
        nsum += __shfl_xor(nsum, off, 64);
    }
    if (lane == 0) out[b] = M + __logf(ps) - nsum;
}

extern "C" void kernel_launch(void* const* d_in, const int* in_sizes, int n_in,
                              void* d_out, int out_size, void* d_ws, size_t ws_size,
                              hipStream_t stream) {
    const float* feat   = (const float*)d_in[0];   // (B,T,S) f32
    const int*   states = (const int*)d_in[1];     // (B,T) i32
    const float* mask   = (const float*)d_in[2];   // (B,T) f32
    const float* trans  = (const float*)d_in[3];   // (S,S) f32
    float* out = (float*)d_out;                    // (B,) f32

    crf_fused<<<dim3(B), dim3(64), 0, stream>>>(feat, states, mask, trans, out);
}